// Round 5
// baseline (2616.321 us; speedup 1.0000x reference)
//
#include <hip/hip_runtime.h>

typedef unsigned short u16;
typedef unsigned int   u32;

#define DIM  1024
#define HID  2560
#define NTOK 8192
#define NEXP 4

#define BM 128
#define BN 128
#define BK 32

typedef __attribute__((ext_vector_type(8))) short bf16x8;
typedef __attribute__((ext_vector_type(4))) float f32x4;

// ---------- helpers ----------
__device__ __forceinline__ u16 f2bf(float f) {
  union { float f; u32 u; } c; c.f = f;
  u32 u = c.u;
  return (u16)((u + 0x7fffu + ((u >> 16) & 1u)) >> 16);   // RNE
}
__device__ __forceinline__ float bfval(u16 h) {
  union { u32 i; float f; } c; c.i = ((u32)h) << 16; return c.f;
}
__device__ __forceinline__ float rb(float f) { return bfval(f2bf(f)); }  // round-trip to bf16
__device__ __forceinline__ ushort4 cvt4(float4 v) {
  ushort4 o; o.x = f2bf(v.x); o.y = f2bf(v.y); o.z = f2bf(v.z); o.w = f2bf(v.w);
  return o;
}

// ---------- gating: one wave per token; also zeroes the aux_loss element ----------
__global__ void gate_kernel(const float* __restrict__ X, const float* __restrict__ GW,
                            float* __restrict__ comb, float* __restrict__ out) {
  int gtid = blockIdx.x * blockDim.x + threadIdx.x;
  int tok  = gtid >> 6;
  int lane = gtid & 63;

  if (gtid == 0) out[(size_t)NTOK * DIM] = 0.0f;  // aux_loss = 0

  const float4* xv = (const float4*)(X + (size_t)tok * DIM + lane * 16);
  float4 x0 = xv[0], x1 = xv[1], x2 = xv[2], x3 = xv[3];

  float acc[NEXP];
#pragma unroll
  for (int e = 0; e < NEXP; ++e) {
    const float4* gv = (const float4*)(GW + e * DIM + lane * 16);
    float4 g0 = gv[0], g1 = gv[1], g2 = gv[2], g3 = gv[3];
    float s;
    s  = x0.x * g0.x + x0.y * g0.y + x0.z * g0.z + x0.w * g0.w;
    s += x1.x * g1.x + x1.y * g1.y + x1.z * g1.z + x1.w * g1.w;
    s += x2.x * g2.x + x2.y * g2.y + x2.z * g2.z + x2.w * g2.w;
    s += x3.x * g3.x + x3.y * g3.y + x3.z * g3.z + x3.w * g3.w;
    acc[e] = s;
  }
#pragma unroll
  for (int off = 32; off > 0; off >>= 1) {
#pragma unroll
    for (int e = 0; e < NEXP; ++e) acc[e] += __shfl_xor(acc[e], off);
  }
  if (lane == 0) {
    int i1 = 0;
#pragma unroll
    for (int e = 1; e < NEXP; ++e) if (acc[e] > acc[i1]) i1 = e;
    int i2 = -1;
#pragma unroll
    for (int e = 0; e < NEXP; ++e) {
      if (e == i1) continue;
      if (i2 < 0 || acc[e] > acc[i2]) i2 = e;
    }
    float m  = acc[i1];
    float e1 = __expf(acc[i1] - m), e2 = __expf(acc[i2] - m);
    float inv = 1.f / (e1 + e2);
    float w[NEXP] = {0.f, 0.f, 0.f, 0.f};
    w[i1] = e1 * inv; w[i2] = e2 * inv;
#pragma unroll
    for (int e = 0; e < NEXP; ++e) comb[(size_t)tok * NEXP + e] = w[e];
  }
}

// ---------- GEMM1: h_e = comb_e * silu(x@w1_e^T) * (x@w3_e^T) ----------
__global__ __launch_bounds__(256, 2) void ffn13_kernel(
    const float* __restrict__ X, const float* __restrict__ W1,
    const float* __restrict__ W3, const float* __restrict__ combp,
    int expert, u16* __restrict__ Hout) {
  __shared__ __align__(16) u16 As [BM * BK];
  __shared__ __align__(16) u16 B1s[BN * BK];
  __shared__ __align__(16) u16 B3s[BN * BK];
  __shared__ float s_comb[BM];

  const int tid  = threadIdx.x;
  const int wave = tid >> 6;
  const int lane = tid & 63;
  const int m0 = blockIdx.y * BM;
  const int n0 = blockIdx.x * BN;

  if (tid < BM) s_comb[tid] = combp[(size_t)(m0 + tid) * NEXP + expert];

  const float* gA[4]; const float* g1[4]; const float* g3[4];
  u16 *lA[4], *l1[4], *l3[4];
#pragma unroll
  for (int q = 0; q < 4; ++q) {
    int c = tid + q * 256;
    int row = c >> 3, col = (c & 7) * 4;
    gA[q] = X  + (size_t)(m0 + row) * DIM + col;
    g1[q] = W1 + (size_t)(n0 + row) * DIM + col;
    g3[q] = W3 + (size_t)(n0 + row) * DIM + col;
    lA[q] = &As [c * 4]; l1[q] = &B1s[c * 4]; l3[q] = &B3s[c * 4];
  }

  const int wm = (wave >> 1) * 64, wn = (wave & 1) * 64;
  const int quad = lane >> 4, r = lane & 15;

  f32x4 acc1[4][4], acc3[4][4];
#pragma unroll
  for (int i = 0; i < 4; ++i)
#pragma unroll
    for (int j = 0; j < 4; ++j) {
      acc1[i][j] = (f32x4){0.f, 0.f, 0.f, 0.f};
      acc3[i][j] = (f32x4){0.f, 0.f, 0.f, 0.f};
    }

  for (int k0 = 0; k0 < DIM; k0 += BK) {
    float4 va[4], v1[4], v3[4];
#pragma unroll
    for (int q = 0; q < 4; ++q) {
      va[q] = *(const float4*)gA[q]; gA[q] += BK;
      v1[q] = *(const float4*)g1[q]; g1[q] += BK;
      v3[q] = *(const float4*)g3[q]; g3[q] += BK;
    }
    __syncthreads();
#pragma unroll
    for (int q = 0; q < 4; ++q) {
      *(ushort4*)lA[q] = cvt4(va[q]);
      *(ushort4*)l1[q] = cvt4(v1[q]);
      *(ushort4*)l3[q] = cvt4(v3[q]);
    }
    __syncthreads();

    bf16x8 af[4], b1f[4], b3f[4];
#pragma unroll
    for (int i = 0; i < 4; ++i)
      af[i] = *(const bf16x8*)&As[(wm + i * 16 + r) * BK + quad * 8];
#pragma unroll
    for (int j = 0; j < 4; ++j) {
      b1f[j] = *(const bf16x8*)&B1s[(wn + j * 16 + r) * BK + quad * 8];
      b3f[j] = *(const bf16x8*)&B3s[(wn + j * 16 + r) * BK + quad * 8];
    }
#pragma unroll
    for (int i = 0; i < 4; ++i)
#pragma unroll
      for (int j = 0; j < 4; ++j) {
        acc1[i][j] = __builtin_amdgcn_mfma_f32_16x16x32_bf16(af[i], b1f[j], acc1[i][j], 0, 0, 0);
        acc3[i][j] = __builtin_amdgcn_mfma_f32_16x16x32_bf16(af[i], b3f[j], acc3[i][j], 0, 0, 0);
      }
  }

  // C/D map: col = lane&15, row = quad*4 + reg
#pragma unroll
  for (int i = 0; i < 4; ++i) {
    const int rowb = wm + i * 16 + quad * 4;
#pragma unroll
    for (int rr = 0; rr < 4; ++rr) {
      const float cw = s_comb[rowb + rr];
      u16* orow = Hout + (size_t)(m0 + rowb + rr) * HID + n0 + wn + r;
#pragma unroll
      for (int j = 0; j < 4; ++j) {
        float v1v = acc1[i][j][rr];
        float v3v = acc3[i][j][rr];
        float sig = 1.f / (1.f + __expf(-v1v));
        orow[j * 16] = f2bf(cw * (v1v * sig * v3v));
      }
    }
  }
}

// ---------- GEMM2 (fused over experts): out = sum_e h_e @ w2_e^T, fp32 out ----------
__global__ __launch_bounds__(256, 2) void ffn2_kernel(
    const u16* __restrict__ Hbase, size_t estride,
    const float* __restrict__ W2, float* __restrict__ Out) {
  __shared__ __align__(16) u16 As[BM * BK];
  __shared__ __align__(16) u16 Bs[BN * BK];

  const int tid  = threadIdx.x;
  const int wave = tid >> 6;
  const int lane = tid & 63;
  const int m0 = blockIdx.y * BM;
  const int n0 = blockIdx.x * BN;

  const int cA0 = tid, cA1 = tid + 256;
  const int rA0 = cA0 >> 2, colA0 = (cA0 & 3) * 8;
  const int rA1 = cA1 >> 2, colA1 = (cA1 & 3) * 8;
  u16* lA0 = &As[cA0 * 8]; u16* lA1 = &As[cA1 * 8];

  u16* lB[4]; int rB[4], colB[4];
#pragma unroll
  for (int q = 0; q < 4; ++q) {
    int c = tid + q * 256;
    rB[q] = c >> 3; colB[q] = (c & 7) * 4;
    lB[q] = &Bs[c * 4];
  }

  const int wm = (wave >> 1) * 64, wn = (wave & 1) * 64;
  const int quad = lane >> 4, r = lane & 15;

  f32x4 acc[4][4];
#pragma unroll
  for (int i = 0; i < 4; ++i)
#pragma unroll
    for (int j = 0; j < 4; ++j) acc[i][j] = (f32x4){0.f, 0.f, 0.f, 0.f};

  for (int e = 0; e < NEXP; ++e) {
    const u16* gA0 = Hbase + (size_t)e * estride + (size_t)(m0 + rA0) * HID + colA0;
    const u16* gA1 = Hbase + (size_t)e * estride + (size_t)(m0 + rA1) * HID + colA1;
    const float* gB[4];
#pragma unroll
    for (int q = 0; q < 4; ++q)
      gB[q] = W2 + ((size_t)e * DIM + n0 + rB[q]) * HID + colB[q];

    for (int k0 = 0; k0 < HID; k0 += BK) {
      uint4 a0 = *(const uint4*)gA0; gA0 += BK;
      uint4 a1 = *(const uint4*)gA1; gA1 += BK;
      float4 vb[4];
#pragma unroll
      for (int q = 0; q < 4; ++q) { vb[q] = *(const float4*)gB[q]; gB[q] += BK; }

      __syncthreads();
      *(uint4*)lA0 = a0; *(uint4*)lA1 = a1;
#pragma unroll
      for (int q = 0; q < 4; ++q) *(ushort4*)lB[q] = cvt4(vb[q]);
      __syncthreads();

      bf16x8 af[4], bf[4];
#pragma unroll
      for (int i = 0; i < 4; ++i)
        af[i] = *(const bf16x8*)&As[(wm + i * 16 + r) * BK + quad * 8];
#pragma unroll
      for (int j = 0; j < 4; ++j)
        bf[j] = *(const bf16x8*)&Bs[(wn + j * 16 + r) * BK + quad * 8];
#pragma unroll
      for (int i = 0; i < 4; ++i)
#pragma unroll
        for (int j = 0; j < 4; ++j)
          acc[i][j] = __builtin_amdgcn_mfma_f32_16x16x32_bf16(af[i], bf[j], acc[i][j], 0, 0, 0);
    }
  }

#pragma unroll
  for (int i = 0; i < 4; ++i) {
    const int rowb = wm + i * 16 + quad * 4;
#pragma unroll
    for (int rr = 0; rr < 4; ++rr) {
      float* orow = Out + (size_t)(m0 + rowb + rr) * DIM + n0 + wn + r;
#pragma unroll
      for (int j = 0; j < 4; ++j) orow[j * 16] = acc[i][j][rr];
    }
  }
}

// ---------- diagnostic verify: writes out[0]=1000+code ONLY if self-tests fail ----------
__global__ void verify_kernel(const float* __restrict__ X, const float* __restrict__ GW,
                              const float* __restrict__ W1, const float* __restrict__ W2,
                              const float* __restrict__ W3, const float* __restrict__ comb,
                              const u16* __restrict__ Hbase, size_t estride, int t0_last,
                              float* __restrict__ Out) {
  __shared__ __align__(16) u16 At[512];
  __shared__ __align__(16) u16 Bt[512];
  const int lane = threadIdx.x;
  const int quad = lane >> 4, r = lane & 15;

  // --- Test 1: MFMA triple (A,B,C/D maps) vs exact scalar reference ---
  for (int idx = lane; idx < 512; idx += 64) {
    int m = idx >> 5, k = idx & 31;
    At[idx] = f2bf((float)((m * 37 + k * 101) % 17 - 8) * 0.125f);
    Bt[idx] = f2bf((float)((m * 53 + k * 29) % 19 - 9) * 0.0625f);
  }
  __syncthreads();
  bf16x8 af = *(const bf16x8*)&At[r * 32 + quad * 8];
  bf16x8 bf = *(const bf16x8*)&Bt[r * 32 + quad * 8];
  f32x4 acc = (f32x4){0.f, 0.f, 0.f, 0.f};
  acc = __builtin_amdgcn_mfma_f32_16x16x32_bf16(af, bf, acc, 0, 0, 0);
  float d0 = 0.f, d1 = 0.f;
#pragma unroll
  for (int rr = 0; rr < 4; ++rr) {
    float rdoc = 0.f, rswp = 0.f;
    for (int k = 0; k < 32; ++k) {
      rdoc += bfval(At[(quad * 4 + rr) * 32 + k]) * bfval(Bt[r * 32 + k]);
      rswp += bfval(At[r * 32 + k]) * bfval(Bt[(quad * 4 + rr) * 32 + k]);
    }
    d0 = fmaxf(d0, fabsf(acc[rr] - rdoc));
    d1 = fmaxf(d1, fabsf(acc[rr] - rswp));
  }
#pragma unroll
  for (int off = 32; off > 0; off >>= 1) {
    d0 = fmaxf(d0, __shfl_xor(d0, off));
    d1 = fmaxf(d1, __shfl_xor(d1, off));
  }

  // --- recompute gating for token TV ---
  const int TV = NTOK - 1, LV = TV - t0_last;
  float lg[NEXP];
#pragma unroll
  for (int e = 0; e < NEXP; ++e) {
    float s = 0.f;
    for (int d = 0; d < DIM; ++d) s += X[(size_t)TV * DIM + d] * GW[e * DIM + d];
    lg[e] = s;
  }
  int i1 = 0;
  for (int e = 1; e < NEXP; ++e) if (lg[e] > lg[i1]) i1 = e;
  int i2 = -1;
  for (int e = 0; e < NEXP; ++e) { if (e == i1) continue; if (i2 < 0 || lg[e] > lg[i2]) i2 = e; }
  float e1 = __expf(lg[i1] - lg[i1]), e2 = __expf(lg[i2] - lg[i1]);
  float inv = 1.f / (e1 + e2);
  float cref[NEXP] = {0.f, 0.f, 0.f, 0.f};
  cref[i1] = e1 * inv; cref[i2] = e2 * inv;
  float cstored[NEXP];
  float dgate = 0.f;
#pragma unroll
  for (int e = 0; e < NEXP; ++e) {
    cstored[e] = comb[(size_t)TV * NEXP + e];
    dgate = fmaxf(dgate, fabsf(cstored[e] - cref[e]));
  }

  // --- Test 2: hbuf spot-check, expert 1, cols lane (use stored comb) ---
  float dh = 0.f;
  {
    int c = lane;
    float s1 = 0.f, s3 = 0.f;
    for (int d = 0; d < DIM; ++d) {
      float xv = rb(X[(size_t)TV * DIM + d]);
      s1 += xv * rb(W1[((size_t)1 * HID + c) * DIM + d]);
      s3 += xv * rb(W3[((size_t)1 * HID + c) * DIM + d]);
    }
    float sig = 1.f / (1.f + __expf(-s1));
    float href = cstored[1] * (s1 * sig * s3);
    float hgot = bfval(Hbase[(size_t)1 * estride + (size_t)LV * HID + c]);
    dh = fabsf(hgot - href);
  }
#pragma unroll
  for (int off = 32; off > 0; off >>= 1) dh = fmaxf(dh, __shfl_xor(dh, off));

  // --- Test 3: out spot-check, cols lane ---
  float dout = 0.f;
  {
    int d = lane;
    float s = 0.f;
    for (int e = 0; e < NEXP; ++e) {
      float se = 0.f;
      for (int h = 0; h < HID; ++h)
        se += bfval(Hbase[(size_t)e * estride + (size_t)LV * HID + h]) *
              rb(W2[((size_t)e * DIM + d) * HID + h]);
      s += se;
    }
    dout = fabsf(Out[(size_t)TV * DIM + d] - s);
  }
#pragma unroll
  for (int off = 32; off > 0; off >>= 1) dout = fmaxf(dout, __shfl_xor(dout, off));

  if (lane == 0) {
    int code = 0;
    if (d0 > 1e-3f) code += 100;
    if (d0 > 1e-3f && d1 <= 1e-3f) code += 200;
    if (dh > 0.1f) code += 400;
    if (dout > 0.15f) code += 800;
    if (dgate > 1e-3f) code += 1600;
    if (code) Out[0] = 1000.0f + (float)code;
  }
}

__global__ void ws_marker_kernel(float* __restrict__ Out, float v) {
  if (threadIdx.x == 0 && blockIdx.x == 0) Out[0] = v;
}

extern "C" void kernel_launch(void* const* d_in, const int* in_sizes, int n_in,
                              void* d_out, int out_size, void* d_ws, size_t ws_size,
                              hipStream_t stream) {
  const float* x  = (const float*)d_in[0];
  const float* gw = (const float*)d_in[1];
  const float* w1 = (const float*)d_in[2];
  const float* w2 = (const float*)d_in[3];
  const float* w3 = (const float*)d_in[4];
  float* out = (float*)d_out;

  char* ws = (char*)d_ws;
  float* comb  = (float*)ws;            // 128 KiB
  u16*   hbase = (u16*)(ws + 131072);

  const size_t min_ws = 131072 + (size_t)NEXP * 128 * HID * sizeof(u16);
  if (ws_size < min_ws) {  // diagnostic marker: 5000 + ws MB
    float v = 5000.0f + (float)(ws_size >> 20 > 999 ? 999 : ws_size >> 20);
    ws_marker_kernel<<<dim3(1), dim3(64), 0, stream>>>(out, v);
    return;
  }

  size_t avail  = ws_size - 131072;
  size_t tokcap = avail / ((size_t)NEXP * HID * sizeof(u16));
  int Tc = (int)(tokcap > NTOK ? NTOK : tokcap);
  Tc &= ~127;
  const size_t estride = (size_t)Tc * HID;

  gate_kernel<<<dim3(NTOK / 4), dim3(256), 0, stream>>>(x, gw, comb, out);

  for (int t0 = 0; t0 < NTOK; t0 += Tc) {
    int Tcur = NTOK - t0; if (Tcur > Tc) Tcur = Tc;
    for (int e = 0; e < NEXP; ++e) {
      const float* w1e = w1 + (size_t)e * HID * DIM;
      const float* w3e = w3 + (size_t)e * HID * DIM;
      ffn13_kernel<<<dim3(HID / BN, Tcur / BM), dim3(256), 0, stream>>>(
          x + (size_t)t0 * DIM, w1e, w3e, comb + (size_t)t0 * NEXP, e,
          hbase + (size_t)e * estride);
    }
    ffn2_kernel<<<dim3(DIM / BN, Tcur / BM), dim3(256), 0, stream>>>(
        hbase, estride, w2, out + (size_t)t0 * DIM);
  }

  int t0_last = ((NTOK - 1) / Tc) * Tc;
  verify_kernel<<<dim3(1), dim3(64), 0, stream>>>(
      x, gw, w1, w2, w3, comb, hbase, estride, t0_last, out);
}

// Round 6
// 953.420 us; speedup vs baseline: 2.7441x; 2.7441x over previous
//
#include <hip/hip_runtime.h>

typedef unsigned short u16;
typedef unsigned int   u32;

#define DIM  1024
#define HID  2560
#define NTOK 8192
#define NEXP 4

#define BM 128
#define BN 128
#define BK 32

typedef __attribute__((ext_vector_type(8))) short bf16x8;
typedef __attribute__((ext_vector_type(4))) float f32x4;

// ---------- helpers ----------
__device__ __forceinline__ void async16(const void* g, void* l) {
  // global -> LDS direct copy, 16 B/lane; LDS dest = wave-uniform base + lane*16
  __builtin_amdgcn_global_load_lds((const __attribute__((address_space(1))) u32*)g,
                                   (__attribute__((address_space(3))) u32*)l,
                                   16, 0, 0);
}
__device__ __forceinline__ u16 f2bf(float f) {
  union { float f; u32 u; } c; c.f = f;
  u32 u = c.u;
  return (u16)((u + 0x7fffu + ((u >> 16) & 1u)) >> 16);   // RNE
}
__device__ __forceinline__ ushort4 cvt4(float4 v) {
  ushort4 o; o.x = f2bf(v.x); o.y = f2bf(v.y); o.z = f2bf(v.z); o.w = f2bf(v.w);
  return o;
}

// ---------- one-time fp32 -> bf16 tensor conversion ----------
__global__ void cvt_kernel(const float* __restrict__ in, u16* __restrict__ out, int n4) {
  int i = blockIdx.x * blockDim.x + threadIdx.x;
  if (i < n4) ((ushort4*)out)[i] = cvt4(((const float4*)in)[i]);
}

// ---------- gating: one wave per token; also zeroes aux_loss ----------
__global__ void gate_kernel(const float* __restrict__ X, const float* __restrict__ GW,
                            float* __restrict__ comb, float* __restrict__ out) {
  int gtid = blockIdx.x * blockDim.x + threadIdx.x;
  int tok  = gtid >> 6;
  int lane = gtid & 63;

  if (gtid == 0) out[(size_t)NTOK * DIM] = 0.0f;  // aux_loss = 0

  const float4* xv = (const float4*)(X + (size_t)tok * DIM + lane * 16);
  float4 x0 = xv[0], x1 = xv[1], x2 = xv[2], x3 = xv[3];

  float acc[NEXP];
#pragma unroll
  for (int e = 0; e < NEXP; ++e) {
    const float4* gv = (const float4*)(GW + e * DIM + lane * 16);
    float4 g0 = gv[0], g1 = gv[1], g2 = gv[2], g3 = gv[3];
    float s;
    s  = x0.x * g0.x + x0.y * g0.y + x0.z * g0.z + x0.w * g0.w;
    s += x1.x * g1.x + x1.y * g1.y + x1.z * g1.z + x1.w * g1.w;
    s += x2.x * g2.x + x2.y * g2.y + x2.z * g2.z + x2.w * g2.w;
    s += x3.x * g3.x + x3.y * g3.y + x3.z * g3.z + x3.w * g3.w;
    acc[e] = s;
  }
#pragma unroll
  for (int off = 32; off > 0; off >>= 1) {
#pragma unroll
    for (int e = 0; e < NEXP; ++e) acc[e] += __shfl_xor(acc[e], off);
  }
  if (lane == 0) {
    int i1 = 0;
#pragma unroll
    for (int e = 1; e < NEXP; ++e) if (acc[e] > acc[i1]) i1 = e;
    int i2 = -1;
#pragma unroll
    for (int e = 0; e < NEXP; ++e) {
      if (e == i1) continue;
      if (i2 < 0 || acc[e] > acc[i2]) i2 = e;
    }
    float m  = acc[i1];
    float e1 = __expf(acc[i1] - m), e2 = __expf(acc[i2] - m);
    float inv = 1.f / (e1 + e2);
    float w[NEXP] = {0.f, 0.f, 0.f, 0.f};
    w[i1] = e1 * inv; w[i2] = e2 * inv;
#pragma unroll
    for (int e = 0; e < NEXP; ++e) comb[(size_t)tok * NEXP + e] = w[e];
  }
}

// ---------- GEMM1: h_e = comb_e * silu(x@w1_e^T) * (x@w3_e^T) ----------
// A (x) fp32 -> cvt staging; B1/B3 bf16 (pre-converted) -> async16 staging.
__global__ __launch_bounds__(256, 2) void ffn13_kernel(
    const float* __restrict__ X,    // chunk base, rows stride DIM (fp32)
    const u16* __restrict__ W1,     // [HID][DIM] bf16 expert slice
    const u16* __restrict__ W3,     // [HID][DIM] bf16
    const float* __restrict__ combp,// chunk base, [tok][NEXP]
    int expert,
    u16* __restrict__ Hout)         // chunk-local [Tcur][HID] bf16
{
  __shared__ __align__(16) u16 As [BM * BK];
  __shared__ __align__(16) u16 B1s[BN * BK];
  __shared__ __align__(16) u16 B3s[BN * BK];
  __shared__ float s_comb[BM];

  const int tid  = threadIdx.x;
  const int wave = tid >> 6;
  const int lane = tid & 63;
  const int m0 = blockIdx.y * BM;
  const int n0 = blockIdx.x * BN;

  if (tid < BM) s_comb[tid] = combp[(size_t)(m0 + tid) * NEXP + expert];

  // A staging (fp32): 1024 chunks of 4 floats; thread t owns chunks t+q*256.
  const float* gA[4]; u16* lA[4];
#pragma unroll
  for (int q = 0; q < 4; ++q) {
    int c = tid + q * 256;
    gA[q] = X + (size_t)(m0 + (c >> 3)) * DIM + (c & 7) * 4;
    lA[q] = &As[c * 4];
  }
  // B staging (bf16, async16): 8x 1KB chunks; wave w owns chunks 2w, 2w+1.
  const int lr = lane >> 2;        // row within 16-row chunk
  const int lc = (lane & 3) * 8;   // k-elem offset
  const u16* p1[2]; const u16* p3[2]; u16 *l1[2], *l3[2];
#pragma unroll
  for (int t = 0; t < 2; ++t) {
    int c = wave * 2 + t;
    p1[t] = W1 + (size_t)(n0 + c * 16 + lr) * DIM + lc;
    p3[t] = W3 + (size_t)(n0 + c * 16 + lr) * DIM + lc;
    l1[t] = &B1s[c * 512];
    l3[t] = &B3s[c * 512];
  }

  const int wm = (wave >> 1) * 64, wn = (wave & 1) * 64;
  const int quad = lane >> 4, r = lane & 15;

  f32x4 acc1[4][4], acc3[4][4];
#pragma unroll
  for (int i = 0; i < 4; ++i)
#pragma unroll
    for (int j = 0; j < 4; ++j) {
      acc1[i][j] = (f32x4){0.f, 0.f, 0.f, 0.f};
      acc3[i][j] = (f32x4){0.f, 0.f, 0.f, 0.f};
    }

  for (int k0 = 0; k0 < DIM; k0 += BK) {
    float4 va[4];
#pragma unroll
    for (int q = 0; q < 4; ++q) { va[q] = *(const float4*)gA[q]; gA[q] += BK; }

    __syncthreads();               // previous iteration's LDS reads complete
#pragma unroll
    for (int q = 0; q < 4; ++q) *(ushort4*)lA[q] = cvt4(va[q]);
#pragma unroll
    for (int t = 0; t < 2; ++t) {
      async16(p1[t], l1[t]); p1[t] += BK;
      async16(p3[t], l3[t]); p3[t] += BK;
    }
    __syncthreads();               // ds_writes + async16 drained

    bf16x8 af[4], b1f[4], b3f[4];
#pragma unroll
    for (int i = 0; i < 4; ++i)
      af[i] = *(const bf16x8*)&As[(wm + i * 16 + r) * BK + quad * 8];
#pragma unroll
    for (int j = 0; j < 4; ++j) {
      b1f[j] = *(const bf16x8*)&B1s[(wn + j * 16 + r) * BK + quad * 8];
      b3f[j] = *(const bf16x8*)&B3s[(wn + j * 16 + r) * BK + quad * 8];
    }
#pragma unroll
    for (int i = 0; i < 4; ++i)
#pragma unroll
      for (int j = 0; j < 4; ++j) {
        acc1[i][j] = __builtin_amdgcn_mfma_f32_16x16x32_bf16(af[i], b1f[j], acc1[i][j], 0, 0, 0);
        acc3[i][j] = __builtin_amdgcn_mfma_f32_16x16x32_bf16(af[i], b3f[j], acc3[i][j], 0, 0, 0);
      }
  }

  // C/D map: col = lane&15, row = quad*4 + reg
#pragma unroll
  for (int i = 0; i < 4; ++i) {
    const int rowb = wm + i * 16 + quad * 4;
#pragma unroll
    for (int rr = 0; rr < 4; ++rr) {
      const float cw = s_comb[rowb + rr];
      u16* orow = Hout + (size_t)(m0 + rowb + rr) * HID + n0 + wn + r;
#pragma unroll
      for (int j = 0; j < 4; ++j) {
        float v1v = acc1[i][j][rr];
        float v3v = acc3[i][j][rr];
        float sig = 1.f / (1.f + __expf(-v1v));
        orow[j * 16] = f2bf(cw * (v1v * sig * v3v));
      }
    }
  }
}

// ---------- GEMM2 (fused over experts): out = sum_e h_e @ w2b_e^T, fp32 out ----------
// Both A (hbuf) and B (w2b) bf16 -> fully async16 staging.
__global__ __launch_bounds__(256, 2) void ffn2_kernel(
    const u16* __restrict__ Hbase,  // 4 chunk-local buffers, expert stride = estride elems
    size_t estride,
    const u16* __restrict__ W2b,    // [NEXP][DIM][HID] bf16
    float* __restrict__ Out)        // chunk base, rows stride DIM
{
  __shared__ __align__(16) u16 As[BM * BK];
  __shared__ __align__(16) u16 Bs[BN * BK];

  const int tid  = threadIdx.x;
  const int wave = tid >> 6;
  const int lane = tid & 63;
  const int m0 = blockIdx.y * BM;
  const int n0 = blockIdx.x * BN;

  const int lr = lane >> 2;
  const int lc = (lane & 3) * 8;
  const int c0 = wave * 2, c1 = wave * 2 + 1;
  u16* la0 = &As[c0 * 512]; u16* la1 = &As[c1 * 512];
  u16* lb0 = &Bs[c0 * 512]; u16* lb1 = &Bs[c1 * 512];

  const int wm = (wave >> 1) * 64, wn = (wave & 1) * 64;
  const int quad = lane >> 4, r = lane & 15;

  f32x4 acc[4][4];
#pragma unroll
  for (int i = 0; i < 4; ++i)
#pragma unroll
    for (int j = 0; j < 4; ++j) acc[i][j] = (f32x4){0.f, 0.f, 0.f, 0.f};

  for (int e = 0; e < NEXP; ++e) {
    const u16* pa0 = Hbase + (size_t)e * estride + (size_t)(m0 + c0 * 16 + lr) * HID + lc;
    const u16* pa1 = Hbase + (size_t)e * estride + (size_t)(m0 + c1 * 16 + lr) * HID + lc;
    const u16* pb0 = W2b + ((size_t)e * DIM + n0 + c0 * 16 + lr) * HID + lc;
    const u16* pb1 = W2b + ((size_t)e * DIM + n0 + c1 * 16 + lr) * HID + lc;

    for (int k0 = 0; k0 < HID; k0 += BK) {
      __syncthreads();
      async16(pa0, la0); pa0 += BK;
      async16(pa1, la1); pa1 += BK;
      async16(pb0, lb0); pb0 += BK;
      async16(pb1, lb1); pb1 += BK;
      __syncthreads();

      bf16x8 af[4], bf[4];
#pragma unroll
      for (int i = 0; i < 4; ++i)
        af[i] = *(const bf16x8*)&As[(wm + i * 16 + r) * BK + quad * 8];
#pragma unroll
      for (int j = 0; j < 4; ++j)
        bf[j] = *(const bf16x8*)&Bs[(wn + j * 16 + r) * BK + quad * 8];
#pragma unroll
      for (int i = 0; i < 4; ++i)
#pragma unroll
        for (int j = 0; j < 4; ++j)
          acc[i][j] = __builtin_amdgcn_mfma_f32_16x16x32_bf16(af[i], bf[j], acc[i][j], 0, 0, 0);
    }
  }

#pragma unroll
  for (int i = 0; i < 4; ++i) {
    const int rowb = wm + i * 16 + quad * 4;
#pragma unroll
    for (int rr = 0; rr < 4; ++rr) {
      float* orow = Out + (size_t)(m0 + rowb + rr) * DIM + n0 + wn + r;
#pragma unroll
      for (int j = 0; j < 4; ++j) orow[j * 16] = acc[i][j][rr];
    }
  }
}

__global__ void ws_marker_kernel(float* __restrict__ Out, float v) {
  if (threadIdx.x == 0 && blockIdx.x == 0) Out[0] = v;
}

extern "C" void kernel_launch(void* const* d_in, const int* in_sizes, int n_in,
                              void* d_out, int out_size, void* d_ws, size_t ws_size,
                              hipStream_t stream) {
  const float* x  = (const float*)d_in[0];
  const float* gw = (const float*)d_in[1];
  const float* w1 = (const float*)d_in[2];
  const float* w2 = (const float*)d_in[3];
  const float* w3 = (const float*)d_in[4];
  float* out = (float*)d_out;

  // ws layout: comb 128 KiB | w1b 20 MiB | w3b 20 MiB | w2b 20 MiB | hbuf (rest)
  const size_t WELEMS = (size_t)NEXP * HID * DIM;        // 10.49M elems per weight
  const size_t WBYTES = WELEMS * sizeof(u16);            // 20 MiB
  char* ws = (char*)d_ws;
  float* comb  = (float*)ws;
  u16*   w1b   = (u16*)(ws + 131072);
  u16*   w3b   = (u16*)(ws + 131072 + WBYTES);
  u16*   w2b   = (u16*)(ws + 131072 + 2 * WBYTES);
  u16*   hbase = (u16*)(ws + 131072 + 3 * WBYTES);
  const size_t fixed = 131072 + 3 * WBYTES;

  const size_t min_ws = fixed + (size_t)NEXP * BM * HID * sizeof(u16);
  if (ws_size < min_ws) {  // diagnostic marker: 5000 + ws MB (evidence says ws >= 84MB; won't fire)
    float v = 5000.0f + (float)((ws_size >> 20) > 999 ? 999 : (ws_size >> 20));
    ws_marker_kernel<<<dim3(1), dim3(64), 0, stream>>>(out, v);
    return;
  }

  size_t tokcap = (ws_size - fixed) / ((size_t)NEXP * HID * sizeof(u16));
  int Tc = (int)(tokcap > NTOK ? NTOK : tokcap);
  Tc &= ~127;
  const size_t estride = (size_t)Tc * HID;

  // one-time weight conversion fp32 -> bf16 (re-done every call; ws is re-poisoned)
  {
    int n4 = (int)(WELEMS / 4);
    int blocks = (n4 + 255) / 256;
    cvt_kernel<<<dim3(blocks), dim3(256), 0, stream>>>(w1, w1b, n4);
    cvt_kernel<<<dim3(blocks), dim3(256), 0, stream>>>(w3, w3b, n4);
    cvt_kernel<<<dim3(blocks), dim3(256), 0, stream>>>(w2, w2b, n4);
  }

  gate_kernel<<<dim3(NTOK / 4), dim3(256), 0, stream>>>(x, gw, comb, out);

  for (int t0 = 0; t0 < NTOK; t0 += Tc) {
    int Tcur = NTOK - t0; if (Tcur > Tc) Tcur = Tc;
    for (int e = 0; e < NEXP; ++e) {
      ffn13_kernel<<<dim3(HID / BN, Tcur / BM), dim3(256), 0, stream>>>(
          x + (size_t)t0 * DIM, w1b + (size_t)e * HID * DIM, w3b + (size_t)e * HID * DIM,
          comb + (size_t)t0 * NEXP, e, hbase + (size_t)e * estride);
    }
    ffn2_kernel<<<dim3(DIM / BN, Tcur / BM), dim3(256), 0, stream>>>(
        hbase, estride, w2b, out + (size_t)t0 * DIM);
  }
}

// Round 7
// 909.835 us; speedup vs baseline: 2.8756x; 1.0479x over previous
//
#include <hip/hip_runtime.h>

typedef unsigned short u16;
typedef unsigned int   u32;

#define DIM  1024
#define HID  2560
#define NTOK 8192
#define NEXP 4

#define BM 128
#define BN 128
#define BK 32

typedef __attribute__((ext_vector_type(8))) short bf16x8;
typedef __attribute__((ext_vector_type(4))) float f32x4;

// ---------- helpers ----------
__device__ __forceinline__ void async16(const void* g, void* l) {
  __builtin_amdgcn_global_load_lds((const __attribute__((address_space(1))) u32*)g,
                                   (__attribute__((address_space(3))) u32*)l,
                                   16, 0, 0);
}
__device__ __forceinline__ u16 f2bf(float f) {
  union { float f; u32 u; } c; c.f = f;
  u32 u = c.u;
  return (u16)((u + 0x7fffu + ((u >> 16) & 1u)) >> 16);   // RNE
}
__device__ __forceinline__ ushort4 cvt4(float4 v) {
  ushort4 o; o.x = f2bf(v.x); o.y = f2bf(v.y); o.z = f2bf(v.z); o.w = f2bf(v.w);
  return o;
}

// ---------- one-time fp32 -> bf16 conversion of w1|w3|w2 (fused, 1 dispatch) ----------
__global__ void cvt3_kernel(const float* __restrict__ w1, const float* __restrict__ w3,
                            const float* __restrict__ w2, u16* __restrict__ w1b,
                            u16* __restrict__ w3b, u16* __restrict__ w2b, int n4each) {
  int i = blockIdx.x * blockDim.x + threadIdx.x;
  if (i < n4each)
    ((ushort4*)w1b)[i] = cvt4(((const float4*)w1)[i]);
  else if (i < 2 * n4each)
    ((ushort4*)w3b)[i - n4each] = cvt4(((const float4*)w3)[i - n4each]);
  else if (i < 3 * n4each)
    ((ushort4*)w2b)[i - 2 * n4each] = cvt4(((const float4*)w2)[i - 2 * n4each]);
}

// ---------- gating: one wave per token; also zeroes aux_loss ----------
__global__ void gate_kernel(const float* __restrict__ X, const float* __restrict__ GW,
                            float* __restrict__ comb, float* __restrict__ out) {
  int gtid = blockIdx.x * blockDim.x + threadIdx.x;
  int tok  = gtid >> 6;
  int lane = gtid & 63;

  if (gtid == 0) out[(size_t)NTOK * DIM] = 0.0f;  // aux_loss = 0

  const float4* xv = (const float4*)(X + (size_t)tok * DIM + lane * 16);
  float4 x0 = xv[0], x1 = xv[1], x2 = xv[2], x3 = xv[3];

  float acc[NEXP];
#pragma unroll
  for (int e = 0; e < NEXP; ++e) {
    const float4* gv = (const float4*)(GW + e * DIM + lane * 16);
    float4 g0 = gv[0], g1 = gv[1], g2 = gv[2], g3 = gv[3];
    float s;
    s  = x0.x * g0.x + x0.y * g0.y + x0.z * g0.z + x0.w * g0.w;
    s += x1.x * g1.x + x1.y * g1.y + x1.z * g1.z + x1.w * g1.w;
    s += x2.x * g2.x + x2.y * g2.y + x2.z * g2.z + x2.w * g2.w;
    s += x3.x * g3.x + x3.y * g3.y + x3.z * g3.z + x3.w * g3.w;
    acc[e] = s;
  }
#pragma unroll
  for (int off = 32; off > 0; off >>= 1) {
#pragma unroll
    for (int e = 0; e < NEXP; ++e) acc[e] += __shfl_xor(acc[e], off);
  }
  if (lane == 0) {
    int i1 = 0;
#pragma unroll
    for (int e = 1; e < NEXP; ++e) if (acc[e] > acc[i1]) i1 = e;
    int i2 = -1;
#pragma unroll
    for (int e = 0; e < NEXP; ++e) {
      if (e == i1) continue;
      if (i2 < 0 || acc[e] > acc[i2]) i2 = e;
    }
    float m  = acc[i1];
    float e1 = __expf(acc[i1] - m), e2 = __expf(acc[i2] - m);
    float inv = 1.f / (e1 + e2);
    float w[NEXP] = {0.f, 0.f, 0.f, 0.f};
    w[i1] = e1 * inv; w[i2] = e2 * inv;
#pragma unroll
    for (int e = 0; e < NEXP; ++e) comb[(size_t)tok * NEXP + e] = w[e];
  }
}

// ---------- GEMM1: h_e = comb_e * silu(x@w1_e^T) * (x@w3_e^T) ----------
__global__ __launch_bounds__(256, 2) void ffn13_kernel(
    const float* __restrict__ X, const u16* __restrict__ W1,
    const u16* __restrict__ W3, const float* __restrict__ combp,
    int expert, u16* __restrict__ Hout) {
  __shared__ __align__(16) u16 As [BM * BK];
  __shared__ __align__(16) u16 B1s[BN * BK];
  __shared__ __align__(16) u16 B3s[BN * BK];
  __shared__ float s_comb[BM];

  const int tid  = threadIdx.x;
  const int wave = tid >> 6;
  const int lane = tid & 63;
  const int m0 = blockIdx.y * BM;
  const int n0 = blockIdx.x * BN;

  if (tid < BM) s_comb[tid] = combp[(size_t)(m0 + tid) * NEXP + expert];

  const float* gA[4]; u16* lA[4];
#pragma unroll
  for (int q = 0; q < 4; ++q) {
    int c = tid + q * 256;
    gA[q] = X + (size_t)(m0 + (c >> 3)) * DIM + (c & 7) * 4;
    lA[q] = &As[c * 4];
  }
  const int lr = lane >> 2;
  const int lc = (lane & 3) * 8;
  const u16* p1[2]; const u16* p3[2]; u16 *l1[2], *l3[2];
#pragma unroll
  for (int t = 0; t < 2; ++t) {
    int c = wave * 2 + t;
    p1[t] = W1 + (size_t)(n0 + c * 16 + lr) * DIM + lc;
    p3[t] = W3 + (size_t)(n0 + c * 16 + lr) * DIM + lc;
    l1[t] = &B1s[c * 512];
    l3[t] = &B3s[c * 512];
  }

  const int wm = (wave >> 1) * 64, wn = (wave & 1) * 64;
  const int quad = lane >> 4, r = lane & 15;

  f32x4 acc1[4][4], acc3[4][4];
#pragma unroll
  for (int i = 0; i < 4; ++i)
#pragma unroll
    for (int j = 0; j < 4; ++j) {
      acc1[i][j] = (f32x4){0.f, 0.f, 0.f, 0.f};
      acc3[i][j] = (f32x4){0.f, 0.f, 0.f, 0.f};
    }

  for (int k0 = 0; k0 < DIM; k0 += BK) {
    float4 va[4];
#pragma unroll
    for (int q = 0; q < 4; ++q) { va[q] = *(const float4*)gA[q]; gA[q] += BK; }

    __syncthreads();
#pragma unroll
    for (int q = 0; q < 4; ++q) *(ushort4*)lA[q] = cvt4(va[q]);
#pragma unroll
    for (int t = 0; t < 2; ++t) {
      async16(p1[t], l1[t]); p1[t] += BK;
      async16(p3[t], l3[t]); p3[t] += BK;
    }
    __syncthreads();

    bf16x8 af[4], b1f[4], b3f[4];
#pragma unroll
    for (int i = 0; i < 4; ++i)
      af[i] = *(const bf16x8*)&As[(wm + i * 16 + r) * BK + quad * 8];
#pragma unroll
    for (int j = 0; j < 4; ++j) {
      b1f[j] = *(const bf16x8*)&B1s[(wn + j * 16 + r) * BK + quad * 8];
      b3f[j] = *(const bf16x8*)&B3s[(wn + j * 16 + r) * BK + quad * 8];
    }
#pragma unroll
    for (int i = 0; i < 4; ++i)
#pragma unroll
      for (int j = 0; j < 4; ++j) {
        acc1[i][j] = __builtin_amdgcn_mfma_f32_16x16x32_bf16(af[i], b1f[j], acc1[i][j], 0, 0, 0);
        acc3[i][j] = __builtin_amdgcn_mfma_f32_16x16x32_bf16(af[i], b3f[j], acc3[i][j], 0, 0, 0);
      }
  }

#pragma unroll
  for (int i = 0; i < 4; ++i) {
    const int rowb = wm + i * 16 + quad * 4;
#pragma unroll
    for (int rr = 0; rr < 4; ++rr) {
      const float cw = s_comb[rowb + rr];
      u16* orow = Hout + (size_t)(m0 + rowb + rr) * HID + n0 + wn + r;
#pragma unroll
      for (int j = 0; j < 4; ++j) {
        float v1v = acc1[i][j][rr];
        float v3v = acc3[i][j][rr];
        float sig = 1.f / (1.f + __expf(-v1v));
        orow[j * 16] = f2bf(cw * (v1v * sig * v3v));
      }
    }
  }
}

// ---------- GEMM2 (fused over experts): out = sum_e h_e @ w2b_e^T ----------
// 1-D grid, XCD-stripe swizzle: xcd = bid&7 owns m-stripe, n cycles fastest
// so the 8 n-blocks sharing an A-tile run on ONE XCD (per-XCD L2 reuse).
__global__ __launch_bounds__(256, 2) void ffn2_kernel(
    const u16* __restrict__ Hbase, size_t estride, int Mb,
    const u16* __restrict__ W2b, float* __restrict__ Out) {
  const int bid   = blockIdx.x;
  const int Mpad  = gridDim.x >> 3;     // padded m-block count (multiple of 8)
  const int stripe = Mpad >> 3;         // m-blocks per XCD
  const int xcd = bid & 7;
  const int k   = bid >> 3;             // [0, Mpad): per-XCD sequence
  const int mb  = xcd * stripe + (k >> 3);
  const int nb  = k & 7;
  if (mb >= Mb) return;
  const int m0 = mb * BM;
  const int n0 = nb * BN;

  __shared__ __align__(16) u16 As[BM * BK];
  __shared__ __align__(16) u16 Bs[BN * BK];

  const int tid  = threadIdx.x;
  const int wave = tid >> 6;
  const int lane = tid & 63;

  const int lr = lane >> 2;
  const int lc = (lane & 3) * 8;
  const int c0 = wave * 2, c1 = wave * 2 + 1;
  u16* la0 = &As[c0 * 512]; u16* la1 = &As[c1 * 512];
  u16* lb0 = &Bs[c0 * 512]; u16* lb1 = &Bs[c1 * 512];

  const int wm = (wave >> 1) * 64, wn = (wave & 1) * 64;
  const int quad = lane >> 4, r = lane & 15;

  f32x4 acc[4][4];
#pragma unroll
  for (int i = 0; i < 4; ++i)
#pragma unroll
    for (int j = 0; j < 4; ++j) acc[i][j] = (f32x4){0.f, 0.f, 0.f, 0.f};

  for (int e = 0; e < NEXP; ++e) {
    const u16* pa0 = Hbase + (size_t)e * estride + (size_t)(m0 + c0 * 16 + lr) * HID + lc;
    const u16* pa1 = Hbase + (size_t)e * estride + (size_t)(m0 + c1 * 16 + lr) * HID + lc;
    const u16* pb0 = W2b + ((size_t)e * DIM + n0 + c0 * 16 + lr) * HID + lc;
    const u16* pb1 = W2b + ((size_t)e * DIM + n0 + c1 * 16 + lr) * HID + lc;

    for (int k0 = 0; k0 < HID; k0 += BK) {
      __syncthreads();
      async16(pa0, la0); pa0 += BK;
      async16(pa1, la1); pa1 += BK;
      async16(pb0, lb0); pb0 += BK;
      async16(pb1, lb1); pb1 += BK;
      __syncthreads();

      bf16x8 af[4], bf[4];
#pragma unroll
      for (int i = 0; i < 4; ++i)
        af[i] = *(const bf16x8*)&As[(wm + i * 16 + r) * BK + quad * 8];
#pragma unroll
      for (int j = 0; j < 4; ++j)
        bf[j] = *(const bf16x8*)&Bs[(wn + j * 16 + r) * BK + quad * 8];
#pragma unroll
      for (int i = 0; i < 4; ++i)
#pragma unroll
        for (int j = 0; j < 4; ++j)
          acc[i][j] = __builtin_amdgcn_mfma_f32_16x16x32_bf16(af[i], bf[j], acc[i][j], 0, 0, 0);
    }
  }

#pragma unroll
  for (int i = 0; i < 4; ++i) {
    const int rowb = wm + i * 16 + quad * 4;
#pragma unroll
    for (int rr = 0; rr < 4; ++rr) {
      float* orow = Out + (size_t)(m0 + rowb + rr) * DIM + n0 + wn + r;
#pragma unroll
      for (int j = 0; j < 4; ++j) orow[j * 16] = acc[i][j][rr];
    }
  }
}

__global__ void ws_marker_kernel(float* __restrict__ Out, float v) {
  if (threadIdx.x == 0 && blockIdx.x == 0) Out[0] = v;
}

extern "C" void kernel_launch(void* const* d_in, const int* in_sizes, int n_in,
                              void* d_out, int out_size, void* d_ws, size_t ws_size,
                              hipStream_t stream) {
  const float* x  = (const float*)d_in[0];
  const float* gw = (const float*)d_in[1];
  const float* w1 = (const float*)d_in[2];
  const float* w2 = (const float*)d_in[3];
  const float* w3 = (const float*)d_in[4];
  float* out = (float*)d_out;

  // ws layout: comb 128 KiB | w1b 20 MiB | w3b 20 MiB | w2b 20 MiB | hbuf (rest)
  const size_t WELEMS = (size_t)NEXP * HID * DIM;
  const size_t WBYTES = WELEMS * sizeof(u16);
  char* ws = (char*)d_ws;
  float* comb  = (float*)ws;
  u16*   w1b   = (u16*)(ws + 131072);
  u16*   w3b   = (u16*)(ws + 131072 + WBYTES);
  u16*   w2b   = (u16*)(ws + 131072 + 2 * WBYTES);
  u16*   hbase = (u16*)(ws + 131072 + 3 * WBYTES);
  const size_t fixed = 131072 + 3 * WBYTES;

  const size_t min_ws = fixed + (size_t)NEXP * BM * HID * sizeof(u16);
  if (ws_size < min_ws) {
    float v = 5000.0f + (float)((ws_size >> 20) > 999 ? 999 : (ws_size >> 20));
    ws_marker_kernel<<<dim3(1), dim3(64), 0, stream>>>(out, v);
    return;
  }

  size_t tokcap = (ws_size - fixed) / ((size_t)NEXP * HID * sizeof(u16));
  int Tc = (int)(tokcap > NTOK ? NTOK : tokcap);
  Tc &= ~127;
  const size_t estride = (size_t)Tc * HID;

  {
    int n4each = (int)(WELEMS / 4);
    int blocks = (3 * n4each + 255) / 256;
    cvt3_kernel<<<dim3(blocks), dim3(256), 0, stream>>>(w1, w3, w2, w1b, w3b, w2b, n4each);
  }

  gate_kernel<<<dim3(NTOK / 4), dim3(256), 0, stream>>>(x, gw, comb, out);

  for (int t0 = 0; t0 < NTOK; t0 += Tc) {
    int Tcur = NTOK - t0; if (Tcur > Tc) Tcur = Tc;
    for (int e = 0; e < NEXP; ++e) {
      ffn13_kernel<<<dim3(HID / BN, Tcur / BM), dim3(256), 0, stream>>>(
          x + (size_t)t0 * DIM, w1b + (size_t)e * HID * DIM, w3b + (size_t)e * HID * DIM,
          comb + (size_t)t0 * NEXP, e, hbase + (size_t)e * estride);
    }
    int Mb   = Tcur / BM;
    int Mpad = (Mb + 7) & ~7;
    ffn2_kernel<<<dim3(Mpad * 8), dim3(256), 0, stream>>>(
        hbase, estride, Mb, w2b, out + (size_t)t0 * DIM);
  }
}